// Round 1
// baseline (431.971 us; speedup 1.0000x reference)
//
#include <hip/hip_runtime.h>
#include <math.h>

// Router: logits = x@W + b ; p = softmax(logits); top-2 -> (idx, gate)
// x: [4,4096,2048] f32, W: [2048,64] f32, b: [64] f32
// out (float32): [ntok*2] indices-as-float, then [ntok*2] gates.

#define DIM 2048
#define NE 64       // experts == lanes per wave
#define TW 8        // tokens per wave
#define TPB_TOK 32  // tokens per block (4 waves)
#define DC 128      // d-chunk staged in LDS (128*64*4 = 32 KB)

__global__ __launch_bounds__(256, 2) void router_kernel(
    const float* __restrict__ x, const float* __restrict__ W,
    const float* __restrict__ b, float* __restrict__ out, int ntok) {
  __shared__ float ws[DC * NE];
  const int lane = threadIdx.x & 63;
  const int wave = threadIdx.x >> 6;
  const int tok0 = blockIdx.x * TPB_TOK + wave * TW;

  float acc[TW];
#pragma unroll
  for (int t = 0; t < TW; ++t) acc[t] = 0.f;

  for (int dc = 0; dc < DIM; dc += DC) {
    // cooperative stage of W[dc:dc+DC][:] (8192 floats) into LDS, float4
    const float4* wsrc = (const float4*)(W + dc * NE);
    float4* wdst = (float4*)ws;
#pragma unroll
    for (int i = 0; i < (DC * NE / 4) / 256; ++i)
      wdst[i * 256 + threadIdx.x] = wsrc[i * 256 + threadIdx.x];
    __syncthreads();

#pragma unroll 2
    for (int d = 0; d < DC; d += 4) {
      float4 xv[TW];
#pragma unroll
      for (int t = 0; t < TW; ++t)
        xv[t] = *(const float4*)(x + (size_t)(tok0 + t) * DIM + dc + d);
      // lane = expert; ws[(d)*64+lane] is 2-way bank aliasing -> free
      float w0 = ws[(d + 0) * NE + lane];
      float w1 = ws[(d + 1) * NE + lane];
      float w2 = ws[(d + 2) * NE + lane];
      float w3 = ws[(d + 3) * NE + lane];
#pragma unroll
      for (int t = 0; t < TW; ++t)
        acc[t] += xv[t].x * w0 + xv[t].y * w1 + xv[t].z * w2 + xv[t].w * w3;
    }
    __syncthreads();
  }

  const float bias = b[lane];
  const int gate_off = ntok * 2;

#pragma unroll
  for (int t = 0; t < TW; ++t) {
    float logit = acc[t] + bias;

    // top-1 (value, index) butterfly reduce; ties -> lowest index (lax.top_k)
    float v1 = logit; int i1 = lane;
#pragma unroll
    for (int off = 1; off < 64; off <<= 1) {
      float ov = __shfl_xor(v1, off, 64);
      int oi = __shfl_xor(i1, off, 64);
      if (ov > v1 || (ov == v1 && oi < i1)) { v1 = ov; i1 = oi; }
    }
    // top-2: mask out winner
    float v2 = (lane == i1) ? -INFINITY : logit; int i2 = lane;
#pragma unroll
    for (int off = 1; off < 64; off <<= 1) {
      float ov = __shfl_xor(v2, off, 64);
      int oi = __shfl_xor(i2, off, 64);
      if (ov > v2 || (ov == v2 && oi < i2)) { v2 = ov; i2 = oi; }
    }
    // softmax denominator (stable: v1 is the max logit)
    float s = __expf(logit - v1);
#pragma unroll
    for (int off = 1; off < 64; off <<= 1) s += __shfl_xor(s, off, 64);

    if (lane == 0) {
      const int tok = tok0 + t;
      out[tok * 2 + 0] = (float)i1;
      out[tok * 2 + 1] = (float)i2;
      out[gate_off + tok * 2 + 0] = 1.0f / s;            // exp(v1-v1)/s
      out[gate_off + tok * 2 + 1] = __expf(v2 - v1) / s;
    }
  }
}

extern "C" void kernel_launch(void* const* d_in, const int* in_sizes, int n_in,
                              void* d_out, int out_size, void* d_ws, size_t ws_size,
                              hipStream_t stream) {
  const float* x = (const float*)d_in[0];
  const float* W = (const float*)d_in[1];
  const float* b = (const float*)d_in[2];
  float* out = (float*)d_out;
  const int ntok = in_sizes[0] / DIM;      // 16384
  const int blocks = ntok / TPB_TOK;       // 512
  router_kernel<<<blocks, 256, 0, stream>>>(x, W, b, out, ntok);
}

// Round 2
// 353.176 us; speedup vs baseline: 1.2231x; 1.2231x over previous
//
#include <hip/hip_runtime.h>
#include <math.h>

// Router: logits = x@W + b ; softmax; top-2 -> (idx-as-float, gate)
// x: [16384, 2048] f32, W: [2048, 64] f32, b: [64] f32
// out f32: [ntok*2] indices, then [ntok*2] gates.
//
// Structure: lane = token. Block = 64 tokens, 512 threads (8 waves).
//   wave w: expert group eg = w&1 (32 experts), K-quarter kh = w>>1 (512 d's).
// Per d: 32 v_fmac with W from SGPRs (wave-uniform s_load), x from VGPR
// (lane-contiguous ds_read_b128 from LDS, staged coalesced from global).

#define DIM 2048
#define NE 64

__global__ __launch_bounds__(512, 2) void router_kernel(
    const float* __restrict__ x, const float* __restrict__ W,
    const float* __restrict__ b, float* __restrict__ out, int ntok) {
  // Stage buffer: [4 kh][16 m][65 float4] (m-row padded 64->65 float4s
  // so staging writes are 8-way not 16-way conflicted; compute reads are
  // lane-contiguous b128, conflict-free). 66560 B. Reused post-loop for
  // K-reduction (48 KB) + logit matrix (16 KB at offset 48K).
  __shared__ alignas(16) char smem[4 * 16 * 65 * 16];
  float4* xs4 = (float4*)smem;
  float* red = (float*)smem;
  float* lgt = (float*)(smem + 48 * 1024);

  const int tid = threadIdx.x;
  const int lane = tid & 63;
  const int wv = __builtin_amdgcn_readfirstlane(tid >> 6);  // force SGPR
  const int eg = wv & 1;        // expert half: 32 experts
  const int kh = wv >> 1;       // K quarter: 512 d's
  const int ebase = eg * 32;
  const int tok0 = blockIdx.x * 64;

  // ---- prologue: load round 0 into registers (8 float4 / thread) ----
  float4 g[8];
#pragma unroll
  for (int h = 0; h < 8; ++h) {
    int i = h * 512 + tid;
    int m = i & 15, row = i >> 4, tok = row & 63, khs = (row >> 6) & 3;
    g[h] = *(const float4*)(x + (size_t)(tok0 + tok) * DIM + khs * 512 + m * 4);
  }

  float acc[32];
#pragma unroll
  for (int e = 0; e < 32; ++e) acc[e] = 0.f;

  const float4* xsr = xs4 + kh * 16 * 65;

  for (int r = 0; r < 8; ++r) {
    // stage round r regs -> LDS
#pragma unroll
    for (int h = 0; h < 8; ++h) {
      int i = h * 512 + tid;
      int m = i & 15, row = i >> 4, tok = row & 63, khs = (row >> 6) & 3;
      xs4[(khs * 16 + m) * 65 + tok] = g[h];
    }
    __syncthreads();
    // prefetch round r+1 (registers; lands during compute below)
    int rn = (r < 7) ? (r + 1) : 7;
#pragma unroll
    for (int h = 0; h < 8; ++h) {
      int i = h * 512 + tid;
      int m = i & 15, row = i >> 4, tok = row & 63, khs = (row >> 6) & 3;
      g[h] = *(const float4*)(x + (size_t)(tok0 + tok) * DIM + khs * 512 +
                              rn * 64 + m * 4);
    }
    // compute: 64 d's, 32 experts per lane
    const int dbase = kh * 512 + r * 64;  // wave-uniform
#pragma unroll 4
    for (int m = 0; m < 16; ++m) {
      float4 xv = xsr[m * 65 + lane];
      float xa[4] = {xv.x, xv.y, xv.z, xv.w};
      const float* wr = W + (size_t)(dbase + m * 4) * NE + ebase;
#pragma unroll
      for (int j = 0; j < 4; ++j) {
#pragma unroll
        for (int e = 0; e < 32; ++e)
          acc[e] = fmaf(xa[j], wr[j * NE + e], acc[e]);
      }
    }
    __syncthreads();  // all reads of this round done before next stage
  }

  // ---- K-quarter reduction via LDS (transposed [e][tok]: b32 conflict-free)
  if (kh > 0) {
    float* dst = red + ((kh - 1) * 2 + eg) * 32 * 64;
#pragma unroll
    for (int e = 0; e < 32; ++e) dst[e * 64 + lane] = acc[e];
  }
  __syncthreads();
  if (kh == 0) {
#pragma unroll
    for (int e = 0; e < 32; ++e) {
      float s = acc[e];
#pragma unroll
      for (int k = 0; k < 3; ++k)
        s += red[(k * 2 + eg) * 32 * 64 + e * 64 + lane];
      lgt[(ebase + e) * 64 + lane] = s + b[ebase + e];
    }
  }
  __syncthreads();

  // ---- per-token softmax + top-2 (lane = token; 2 waves x 32 tokens) ----
  if (wv < 2 && lane < 32) {
    const int t = wv * 32 + lane;
    float v1 = -INFINITY, v2 = -INFINITY;
    int i1 = 0, i2 = 0;
#pragma unroll
    for (int e = 0; e < 64; ++e) {
      float v = lgt[e * 64 + t];
      if (v > v1) { v2 = v1; i2 = i1; v1 = v; i1 = e; }
      else if (v > v2) { v2 = v; i2 = e; }
    }
    float s = 0.f;
#pragma unroll
    for (int e = 0; e < 64; ++e) s += __expf(lgt[e * 64 + t] - v1);
    const int tok = tok0 + t;
    out[tok * 2 + 0] = (float)i1;
    out[tok * 2 + 1] = (float)i2;
    out[ntok * 2 + tok * 2 + 0] = 1.0f / s;
    out[ntok * 2 + tok * 2 + 1] = __expf(v2 - v1) / s;
  }
}

extern "C" void kernel_launch(void* const* d_in, const int* in_sizes, int n_in,
                              void* d_out, int out_size, void* d_ws, size_t ws_size,
                              hipStream_t stream) {
  const float* x = (const float*)d_in[0];
  const float* W = (const float*)d_in[1];
  const float* b = (const float*)d_in[2];
  float* out = (float*)d_out;
  const int ntok = in_sizes[0] / DIM;   // 16384
  const int blocks = ntok / 64;         // 256
  router_kernel<<<blocks, 512, 0, stream>>>(x, W, b, out, ntok);
}

// Round 3
// 203.761 us; speedup vs baseline: 2.1200x; 1.7333x over previous
//
#include <hip/hip_runtime.h>
#include <hip/hip_bf16.h>
#include <math.h>

// Router: logits = x@W + b ; softmax; top-2 -> (idx-as-float, gate)
// x: [16384, 2048] f32, W: [2048, 64] f32, b: [64] f32
// out f32: [ntok*2] indices, then [ntok*2] gates.
//
// Plan: bf16 hi/lo split GEMM on MFMA (3 products, lo*lo dropped ~1e-5 rel).
//  - wprep_kernel: W -> MFMA B-fragments (hi/lo) in d_ws (512 KB, L2-resident)
//  - router_main: 512 blocks x 4 waves; block = 32 tokens; wave = K-quarter.
//    x streamed global->LDS via global_load_lds(16B), rotated row layout
//    (coalesced global fetch + conflict-free ds_read_b128 A-frag reads).
//    Epilogue: cross-wave K-reduction in LDS, then softmax+top2.

#define DIM 2048
#define NE 64

typedef __attribute__((ext_vector_type(8))) short short8;
typedef __attribute__((ext_vector_type(4))) float floatx4;

__device__ __forceinline__ short bf16bits(float v) {
  __hip_bfloat16 h = __float2bfloat16(v);
  return *(short*)&h;
}
__device__ __forceinline__ float bf16tof(short s) {
  unsigned int u = ((unsigned int)(unsigned short)s) << 16;
  union { unsigned int u; float f; } c; c.u = u;
  return c.f;
}

// ---- W fragment prep: wf[s(64)][n(4)][plane(2)][lane(64)] = short8 ----
// B-frag 16x16x32: lane l holds B[k = s*32 + (l>>4)*8 + j][e = n*16 + (l&15)]
__global__ void wprep_kernel(const float* __restrict__ W, short8* __restrict__ wf) {
  const int s = blockIdx.x >> 2, n = blockIdx.x & 3, l = threadIdx.x;
  const int d0 = s * 32 + (l >> 4) * 8;
  const int e = n * 16 + (l & 15);
  short8 vh, vl;
#pragma unroll
  for (int j = 0; j < 8; ++j) {
    float v = W[(size_t)(d0 + j) * NE + e];
    short h = bf16bits(v);
    vh[j] = h;
    vl[j] = bf16bits(v - bf16tof(h));
  }
  wf[(size_t)((s * 4 + n) * 2 + 0) * 64 + l] = vh;
  wf[(size_t)((s * 4 + n) * 2 + 1) * 64 + l] = vl;
}

__device__ __forceinline__ void async_copy16(const float* g, void* lds) {
  __builtin_amdgcn_global_load_lds(
      (const __attribute__((address_space(1))) unsigned int*)g,
      (__attribute__((address_space(3))) unsigned int*)lds, 16, 0, 0);
}

__global__ __launch_bounds__(256, 2) void router_main(
    const float* __restrict__ x, const short8* __restrict__ wf,
    const float* __restrict__ b, float* __restrict__ out, int ntok) {
  // 4 waves x 2 buffers x 8 KB (32 tok x 64 k fp32, rotated rows) = 64 KB
  __shared__ alignas(16) char smem[65536];
  const int tid = threadIdx.x;
  const int lane = tid & 63;
  const int kq = tid >> 6;       // wave = K-quarter
  const int tok0 = blockIdx.x * 32;
  const int r4 = lane >> 4;      // 0..3
  const int g = lane & 15;

  char* mybuf = smem + kq * 16384;
  const float* xbase = x + (size_t)tok0 * DIM + kq * 512;

  floatx4 acc[2][4];
#pragma unroll
  for (int mt = 0; mt < 2; ++mt)
#pragma unroll
    for (int n = 0; n < 4; ++n) acc[mt][n] = (floatx4){0.f, 0.f, 0.f, 0.f};

  // issue one 64-k chunk (32 tok x 64 k = 8 KB) into buffer sel
  auto issue = [&](int c, int sel) {
    const float* gb = xbase + c * 64;
    char* dst = mybuf + sel * 8192;
#pragma unroll
    for (int p = 0; p < 8; ++p) {
      const int rr = p * 4 + r4;                         // row 0..31
      const float* gp = gb + (size_t)rr * DIM + (((g + rr) & 15) << 2);
      async_copy16(gp, dst + p * 1024);                  // lds = base + lane*16
    }
  };

  issue(0, 0);
  __syncthreads();

  for (int c = 0; c < 8; ++c) {
    if (c < 7) issue(c + 1, (c + 1) & 1);
    const float* bb = (const float*)(mybuf + (c & 1) * 8192);
#pragma unroll
    for (int u = 0; u < 2; ++u) {
      const int sg = kq * 16 + c * 2 + u;   // global kstep
      // W fragments (L2-resident, coalesced 16B/lane)
      const short8* wp = wf + (size_t)sg * 8 * 64;
      short8 Wh[4], Wl[4];
#pragma unroll
      for (int n = 0; n < 4; ++n) {
        Wh[n] = wp[(n * 2 + 0) * 64 + lane];
        Wl[n] = wp[(n * 2 + 1) * 64 + lane];
      }
#pragma unroll
      for (int mt = 0; mt < 2; ++mt) {
        const int rr = mt * 16 + g;         // token row (A: m = lane&15)
        const int G0 = u * 8 + r4 * 2;      // logical 4-float group
        floatx4 a0 = *(const floatx4*)(bb + rr * 64 + (((G0 - rr) & 15) << 2));
        floatx4 a1 = *(const floatx4*)(bb + rr * 64 + (((G0 + 1 - rr) & 15) << 2));
        short8 Ah, Al;
#pragma unroll
        for (int j = 0; j < 4; ++j) {
          short h = bf16bits(a0[j]);
          Ah[j] = h; Al[j] = bf16bits(a0[j] - bf16tof(h));
        }
#pragma unroll
        for (int j = 0; j < 4; ++j) {
          short h = bf16bits(a1[j]);
          Ah[4 + j] = h; Al[4 + j] = bf16bits(a1[j] - bf16tof(h));
        }
#pragma unroll
        for (int n = 0; n < 4; ++n) {
          acc[mt][n] = __builtin_amdgcn_mfma_f32_16x16x32_bf16(Ah, Wh[n], acc[mt][n], 0, 0, 0);
          acc[mt][n] = __builtin_amdgcn_mfma_f32_16x16x32_bf16(Ah, Wl[n], acc[mt][n], 0, 0, 0);
          acc[mt][n] = __builtin_amdgcn_mfma_f32_16x16x32_bf16(Al, Wh[n], acc[mt][n], 0, 0, 0);
        }
      }
    }
    __syncthreads();   // drains DMA for chunk c+1; syncs buffer swap
  }

  // ---- cross-wave K reduction: red[kq][tok][e], stride 66 (bank-spread) ----
  float* red = (float*)smem;                 // 4*32*66*4 = 33792 B
  float* lgt = (float*)(smem + 33792);       // 32*65*4  =  8320 B
#pragma unroll
  for (int mt = 0; mt < 2; ++mt)
#pragma unroll
    for (int n = 0; n < 4; ++n)
#pragma unroll
      for (int r = 0; r < 4; ++r) {
        const int tokl = mt * 16 + r4 * 4 + r;   // C/D: row = (lane>>4)*4+reg
        const int e = n * 16 + g;                // C/D: col = lane&15
        red[(kq * 32 + tokl) * 66 + e] = acc[mt][n][r];
      }
  __syncthreads();

  // ---- softmax + top-2, lane = token ----
  if (tid < 32) {
    const int t = tid;
    float v1 = -INFINITY, v2 = -INFINITY;
    int i1 = 0, i2 = 0;
#pragma unroll 8
    for (int e = 0; e < 64; ++e) {
      float v = red[t * 66 + e] + red[(32 + t) * 66 + e] +
                red[(64 + t) * 66 + e] + red[(96 + t) * 66 + e] + b[e];
      lgt[t * 65 + e] = v;
      if (v > v1) { v2 = v1; i2 = i1; v1 = v; i1 = e; }
      else if (v > v2) { v2 = v; i2 = e; }
    }
    float s = 0.f;
#pragma unroll 8
    for (int e = 0; e < 64; ++e) s += __expf(lgt[t * 65 + e] - v1);
    const int tok = tok0 + t;
    out[tok * 2 + 0] = (float)i1;
    out[tok * 2 + 1] = (float)i2;
    out[ntok * 2 + tok * 2 + 0] = 1.0f / s;
    out[ntok * 2 + tok * 2 + 1] = __expf(v2 - v1) / s;
  }
}

extern "C" void kernel_launch(void* const* d_in, const int* in_sizes, int n_in,
                              void* d_out, int out_size, void* d_ws, size_t ws_size,
                              hipStream_t stream) {
  const float* x = (const float*)d_in[0];
  const float* W = (const float*)d_in[1];
  const float* b = (const float*)d_in[2];
  float* out = (float*)d_out;
  const int ntok = in_sizes[0] / DIM;          // 16384
  short8* wf = (short8*)d_ws;                  // 512 KB of fragments

  wprep_kernel<<<256, 64, 0, stream>>>(W, wf);
  router_main<<<ntok / 32, 256, 0, stream>>>(x, wf, b, out, ntok);
}

// Round 4
// 199.159 us; speedup vs baseline: 2.1690x; 1.0231x over previous
//
#include <hip/hip_runtime.h>
#include <hip/hip_bf16.h>
#include <math.h>

// Router: logits = x@W + b ; softmax; top-2 -> (idx-as-float, gate)
// x: [16384, 2048] f32, W: [2048, 64] f32, b: [64] f32
// out f32: [ntok*2] indices, then [ntok*2] gates.
//
// bf16 hi/lo split GEMM on MFMA (3 products; lo*lo dropped, ~1e-4 abs).
// Barrier-free K-loop: each wave owns a private 2x4KB LDS double buffer,
// streams x via global_load_lds(16B) with per-row rotated layout, and
// pipelines with manual `s_waitcnt vmcnt(4)` (no __syncthreads in loop).

#define DIM 2048
#define NE 64

typedef __attribute__((ext_vector_type(8))) short short8;
typedef __attribute__((ext_vector_type(4))) float floatx4;

__device__ __forceinline__ short bf16bits(float v) {
  __hip_bfloat16 h = __float2bfloat16(v);
  return *(short*)&h;
}
__device__ __forceinline__ float bf16tof(short s) {
  union { unsigned int u; float f; } c;
  c.u = ((unsigned int)(unsigned short)s) << 16;
  return c.f;
}

// ---- W fragment prep: wf[sg(64)][n(4)][plane(2)][lane(64)] = short8 ----
// B-frag 16x16x32: lane l holds B[k = sg*32 + (l>>4)*8 + j][e = n*16 + (l&15)]
__global__ void wprep_kernel(const float* __restrict__ W, short8* __restrict__ wf) {
  const int s = blockIdx.x >> 2, n = blockIdx.x & 3, l = threadIdx.x;
  const int d0 = s * 32 + (l >> 4) * 8;
  const int e = n * 16 + (l & 15);
  short8 vh, vl;
#pragma unroll
  for (int j = 0; j < 8; ++j) {
    float v = W[(size_t)(d0 + j) * NE + e];
    short h = bf16bits(v);
    vh[j] = h;
    vl[j] = bf16bits(v - bf16tof(h));
  }
  wf[(size_t)((s * 4 + n) * 2 + 0) * 64 + l] = vh;
  wf[(size_t)((s * 4 + n) * 2 + 1) * 64 + l] = vl;
}

__device__ __forceinline__ void async_copy16(const float* g, void* lds) {
  __builtin_amdgcn_global_load_lds(
      (const __attribute__((address_space(1))) unsigned int*)g,
      (__attribute__((address_space(3))) unsigned int*)lds, 16, 0, 0);
}

__global__ __launch_bounds__(256, 3) void router_main(
    const float* __restrict__ x, const short8* __restrict__ wf,
    const float* __restrict__ b, float* __restrict__ out, int ntok) {
  // main loop: wave kq uses smem + kq*8192 (2 x 4KB double buffer) = 32 KB
  // epilogue: red[kq(4)][tok(32)][e stride 65] = 33280 B (reuses same smem)
  __shared__ alignas(16) char smem[33280];
  const int tid = threadIdx.x;
  const int lane = tid & 63;
  const int kq = tid >> 6;        // wave = K-quarter (512 d's)
  const int g = lane & 15, r4 = lane >> 4;
  const int tok0 = blockIdx.x * 32;

  char* mybuf = smem + kq * 8192;
  const float* xb = x + (size_t)tok0 * DIM + kq * 512;

  // chunk = 32 tok x 32 k (4 KB). LDS[row][slot G]: G = (kgroup4 + row) & 7
  // (rotation -> conflict-free ds_read_b128; DMA fetch stays 128B-contiguous
  //  per row). Instruction p covers rows p*8..p*8+7.
  auto issue = [&](int c, char* dst) {
    const float* gb = xb + c * 32;
#pragma unroll
    for (int p = 0; p < 4; ++p) {
      const int rr = p * 8 + (lane >> 3);
      const float* gp = gb + (size_t)rr * DIM + ((((lane & 7) - rr) & 7) << 2);
      async_copy16(gp, dst + p * 1024);
    }
  };

  floatx4 acc[2][4];
#pragma unroll
  for (int mt = 0; mt < 2; ++mt)
#pragma unroll
    for (int n = 0; n < 4; ++n) acc[mt][n] = (floatx4){0.f, 0.f, 0.f, 0.f};

  issue(0, mybuf);

  for (int c = 0; c < 16; ++c) {
    // W fragments first (program order: retire before/with our vmcnt wait)
    const int sg = kq * 16 + c;
    const short8* wp = wf + (size_t)sg * 8 * 64;
    short8 Wh[4], Wl[4];
#pragma unroll
    for (int n = 0; n < 4; ++n) {
      Wh[n] = wp[(n * 2 + 0) * 64 + lane];
      Wl[n] = wp[(n * 2 + 1) * 64 + lane];
    }
    if (c < 15) issue(c + 1, mybuf + ((c + 1) & 1) * 4096);
    // chunk c's 4 DMA ops are the oldest outstanding vmem ops ->
    // vmcnt(4) guarantees they landed, while chunk c+1 stays in flight.
    asm volatile("s_waitcnt vmcnt(4)" ::: "memory");

    const float* bb = (const float*)(mybuf + (c & 1) * 4096);
#pragma unroll
    for (int mt = 0; mt < 2; ++mt) {
      const int row = mt * 16 + g;           // A: m = lane&15 (token)
      const int ga0 = r4 * 2;                // A: k-groups (lane>>4)*8 .. +7
      floatx4 a0 = *(const floatx4*)(bb + row * 32 + (((ga0 + 0 + row) & 7) << 2));
      floatx4 a1 = *(const floatx4*)(bb + row * 32 + (((ga0 + 1 + row) & 7) << 2));
      short8 Ah, Al;
#pragma unroll
      for (int j = 0; j < 4; ++j) {
        short h = bf16bits(a0[j]);
        Ah[j] = h; Al[j] = bf16bits(a0[j] - bf16tof(h));
      }
#pragma unroll
      for (int j = 0; j < 4; ++j) {
        short h = bf16bits(a1[j]);
        Ah[4 + j] = h; Al[4 + j] = bf16bits(a1[j] - bf16tof(h));
      }
#pragma unroll
      for (int n = 0; n < 4; ++n) {
        acc[mt][n] = __builtin_amdgcn_mfma_f32_16x16x32_bf16(Ah, Wh[n], acc[mt][n], 0, 0, 0);
        acc[mt][n] = __builtin_amdgcn_mfma_f32_16x16x32_bf16(Ah, Wl[n], acc[mt][n], 0, 0, 0);
        acc[mt][n] = __builtin_amdgcn_mfma_f32_16x16x32_bf16(Al, Wh[n], acc[mt][n], 0, 0, 0);
      }
    }
  }

  // ---- cross-wave K reduction (stride 65: 2-way bank aliasing, free) ----
  __syncthreads();                 // all waves done with stage buffers
  float* red = (float*)smem;
#pragma unroll
  for (int mt = 0; mt < 2; ++mt)
#pragma unroll
    for (int n = 0; n < 4; ++n)
#pragma unroll
      for (int r = 0; r < 4; ++r) {
        const int tokl = mt * 16 + r4 * 4 + r;   // C/D: row = (lane>>4)*4+reg
        const int e = n * 16 + g;                // C/D: col = lane&15
        red[(kq * 32 + tokl) * 65 + e] = acc[mt][n][r];
      }
  __syncthreads();

  // ---- softmax + top-2: token t = kq*8 + (lane&7), experts (lane>>3)*8.. ----
  {
    const int tl = lane & 7, er = lane >> 3;
    const int t = kq * 8 + tl;
    float lv[8];
    float v1 = -INFINITY, v2 = -INFINITY;
    int i1 = 0, i2 = 0;
#pragma unroll
    for (int i = 0; i < 8; ++i) {
      const int e = er * 8 + i;
      float v = red[t * 65 + e] + red[(32 + t) * 65 + e] +
                red[(64 + t) * 65 + e] + red[(96 + t) * 65 + e] + b[e];
      lv[i] = v;
      if (v > v1) { v2 = v1; i2 = i1; v1 = v; i1 = e; }
      else if (v > v2) { v2 = v; i2 = e; }
    }
    // merge top-2 across the 8 expert-lanes (ties -> lowest index)
#pragma unroll
    for (int off = 8; off < 64; off <<= 1) {
      float ov1 = __shfl_xor(v1, off, 64); int oi1 = __shfl_xor(i1, off, 64);
      float ov2 = __shfl_xor(v2, off, 64); int oi2 = __shfl_xor(i2, off, 64);
      bool aw = (v1 > ov1) || (v1 == ov1 && i1 < oi1);
      float nv1 = aw ? v1 : ov1; int ni1 = aw ? i1 : oi1;
      float c2v = aw ? ov1 : v1; int c2i = aw ? oi1 : i1;
      float w2v = aw ? v2 : ov2; int w2i = aw ? i2 : oi2;
      bool sw = (w2v > c2v) || (w2v == c2v && w2i < c2i);
      v2 = sw ? w2v : c2v; i2 = sw ? w2i : c2i;
      v1 = nv1; i1 = ni1;
    }
    float s = 0.f;
#pragma unroll
    for (int i = 0; i < 8; ++i) s += __expf(lv[i] - v1);
#pragma unroll
    for (int off = 8; off < 64; off <<= 1) s += __shfl_xor(s, off, 64);
    if (er == 0) {
      const int tok = tok0 + t;
      out[tok * 2 + 0] = (float)i1;
      out[tok * 2 + 1] = (float)i2;
      out[ntok * 2 + tok * 2 + 0] = 1.0f / s;
      out[ntok * 2 + tok * 2 + 1] = __expf(v2 - v1) / s;
    }
  }
}

extern "C" void kernel_launch(void* const* d_in, const int* in_sizes, int n_in,
                              void* d_out, int out_size, void* d_ws, size_t ws_size,
                              hipStream_t stream) {
  const float* x = (const float*)d_in[0];
  const float* W = (const float*)d_in[1];
  const float* b = (const float*)d_in[2];
  float* out = (float*)d_out;
  const int ntok = in_sizes[0] / DIM;          // 16384
  short8* wf = (short8*)d_ws;                  // 512 KB of W fragments

  wprep_kernel<<<256, 64, 0, stream>>>(W, wf);
  router_main<<<ntok / 32, 256, 0, stream>>>(x, wf, b, out, ntok);
}